// Round 9
// baseline (253.573 us; speedup 1.0000x reference)
//
#include <hip/hip_runtime.h>
#include <hip/hip_bf16.h>
#include <cstdint>
#include <cstddef>

// Problem constants
#define B_  8192
#define D_  256
#define H_  512
#define K_  1280   // D + 2H
#define N_  2560   // 5H
#define NT_ 320    // N-tile: 2 h-groups of (32 h x 5 gates)
#define BM_ 256    // M-tile
#define BK_ 64     // K-step

typedef short short8  __attribute__((ext_vector_type(8)));
typedef float f32x4   __attribute__((ext_vector_type(4)));
typedef float f32x16  __attribute__((ext_vector_type(16)));

__device__ __forceinline__ float sigf(float x)     { return 1.f / (1.f + __expf(-x)); }
__device__ __forceinline__ float tanhfast(float x) { return 1.f - 2.f / (__expf(2.f * x) + 1.f); }

struct WPtrs {
    const float* U[5];
    const float* Wt[5];
    const float* Ws[5];
};

// ---------------------------------------------------------------------------
// FUSED single-launch kernel: prep_w phase -> device-scope grid barrier ->
// R8 GEMM+LSTM phase.
//
// WHY (R8 post-mortem): total-minus-gemm residue is ~132 us in EVERY round
// (R3:145 R5:146 R6:133 R8:132) while gemm itself is pinned 89-100 us and
// memory is exonerated (FETCH 183.7->62.7 MB with zero time change). The
// residue is larger than the GEMM and unattributable from per-dispatch
// counters. This round collapses everything into ONE dispatch to decompose
// it by construction: if total -> ~120-150, the residue was launch/pipeline
// structure; if total stays ~225, it's harness-fixed and the gemm core is
// the only remaining surface.
//
// Grid-barrier safety: 144 KB LDS/block forces 1 block/CU (2x144 > 160 KB),
// grid = 256 = CU count => all blocks co-resident by construction. Barrier =
// device-scope atomicAdd + spin with a ~25 ms clock64 escape hatch (a failed
// barrier then shows as absmax fail, not a hang).
// Cross-XCD WT visibility (no dispatch boundary anymore): __threadfence()
// release (L2 writeback) before arrive; __threadfence() acquire (L2 inv)
// after wait. Per-wave vmcnt drain at __syncthreads covers store completion.
// ---------------------------------------------------------------------------
#define GLD16(gp, lp)                                                              \
    __builtin_amdgcn_global_load_lds(                                              \
        (const __attribute__((address_space(1))) unsigned int*)(gp),               \
        (__attribute__((address_space(3))) unsigned int*)(lp), 16, 0, 0)

__global__ __launch_bounds__(512, 2) void fused_kernel(
    const float* __restrict__ x, const float* __restrict__ ht,
    const float* __restrict__ hs, WPtrs wp, __hip_bfloat16* __restrict__ WT,
    unsigned int* __restrict__ cnt,
    const float* __restrict__ ct, const float* __restrict__ cs,
    const float* __restrict__ bi, const float* __restrict__ bfs,
    const float* __restrict__ bft, const float* __restrict__ bo,
    const float* __restrict__ bc, float* __restrict__ out) {
    __shared__ alignas(16) unsigned short sA[2][BM_ * BK_];  // 64 KB
    __shared__ alignas(16) unsigned short sB[2][NT_ * BK_];  // 80 KB

    int tid = threadIdx.x;
    int bid = blockIdx.x;

    // ================= PREP PHASE (was prep_w_kernel) =================
    // 800 units of (g, 64k x 64h); each 256-thread HALF-block does units
    // hb and hb+512 (hb = bid*2 + half_sel). Prep tiles alias sA[0] (16.9 KB
    // of its 32 KB) -- LDS is unioned across phases, barriers separate them.
    {
        __hip_bfloat16* tbase = reinterpret_cast<__hip_bfloat16*>(&sA[0][0]);
        int half_sel = (tid >= 256) ? 1 : 0;
        __hip_bfloat16* tile = tbase + half_sel * (64 * 66);   // [64][66]
        int tid8 = tid & 255;
        int tk = tid8 >> 6, th = tid8 & 63;
        int hb = bid * 2 + half_sel;
        for (int uu = 0; uu < 2; ++uu) {
            int u = hb + uu * 512;
            bool act = (u < 800);
            const float* src = nullptr; int kl0 = 0, k0u = 0, h0u = 0, gu = 0;
            if (act) {
                int hblk = u & 7;
                int kblk = (u >> 3) % 20;
                gu = u / 160;
                k0u = kblk * 64; h0u = hblk * 64;
                if (k0u < 256)      { src = wp.U[gu];  kl0 = k0u; }
                else if (k0u < 768) { src = wp.Wt[gu]; kl0 = k0u - 256; }
                else                { src = wp.Ws[gu]; kl0 = k0u - 768; }
                for (int r = 0; r < 16; ++r) {
                    int kl = r * 4 + tk;
                    tile[kl * 66 + th] =
                        __float2bfloat16(src[(size_t)(kl0 + kl) * H_ + h0u + th]);
                }
            }
            __syncthreads();
            if (act) {
                for (int r = 0; r < 16; ++r) {
                    int hl = r * 4 + tk;
                    int hh = h0u + hl;
                    int np = (hh >> 5) * 160 + gu * 32 + (hh & 31);
                    WT[(size_t)np * K_ + k0u + th] = tile[th * 66 + hl];
                }
            }
            __syncthreads();
        }
    }

    // ================= GRID BARRIER =================
    if (tid == 0) {
        __threadfence();                                     // release: wb L2
        atomicAdd(cnt, 1u);
        long long t0 = clock64();
        while (__hip_atomic_load(cnt, __ATOMIC_RELAXED, __HIP_MEMORY_SCOPE_AGENT) < 256u) {
            __builtin_amdgcn_s_sleep(32);
            if (clock64() - t0 > 60000000LL) break;          // ~25 ms escape
        }
        __threadfence();                                     // acquire: inv L2
    }
    __syncthreads();

    // ================= GEMM + LSTM PHASE (R8 body) =================
    int m0 = (bid & 31) * BM_;    // m-fast: XCD = bid%8 = m%8 -> A L2-shared
    int n0 = (bid >> 5) * NT_;
    int wid  = tid >> 6, lane = tid & 63;
    int wm   = wid >> 1;         // 0..3: 64-row slice
    int wn   = wid & 1;          // 0..1: 160-col (32-h-group x 5 gates) slice
    int half = lane >> 5, l31 = lane & 31;
    int xr   = l31 & 7;          // read swizzle key (row&7 of all frag rows)

    int hg = (bid >> 5) * 2 + wn;      // 32-h group
    int h  = hg * 32 + l31;            // this lane's h column
    float Bi = bi[h], Bfs = bfs[h], Bft = bft[h], Bo = bo[h], Bc = bc[h];

    f32x16 acc[2][5];
#pragma unroll
    for (int i = 0; i < 2; ++i)
#pragma unroll
        for (int j = 0; j < 5; ++j)
            acc[i][j] = (f32x16)(0.f);

    // ---- staging thread mapping: row srow = tid>>3 (+64/round), chunk p = tid&7.
    int srow = tid >> 3;                 // 0..63
    int pA   = tid & 7;                  // chunk index (8 shorts = 16 B)
    int xk   = srow & 7;                 // write swizzle key (round-invariant)

    // B: global_load_lds, source pre-swizzled, dest linear.
    const __hip_bfloat16* bBase = WT + (size_t)(n0 + srow) * K_ + (pA ^ xk) * 8;
    int t8 = tid * 8;
#define STG_B(dst, koff)                                                          \
    do {                                                                          \
        _Pragma("unroll")                                                         \
        for (int r_ = 0; r_ < 5; ++r_)                                            \
            GLD16(bBase + (size_t)r_ * 64 * K_ + (koff), (dst) + r_ * 4096 + t8); \
    } while (0)

    // A: per-thread fp32 bases into the three sources (plain chunk pA; the
    // swizzle is applied on the WRITE side so ds_write banks spread by xor).
    int rowIdx = m0 + srow;
    const float* xB  = x  + (size_t)rowIdx * D_ + pA * 8;
    const float* htB = ht + (size_t)rowIdx * H_ + pA * 8;
    const float* hsB = hs + (size_t)rowIdx * H_ + pA * 8;
    int aWr = srow * 64 + (pA ^ xk) * 8;     // LDS dst (shorts), +4096/round

#define A_SRC(k0n, aP, aStr)                                                      \
    do {                                                                          \
        if ((k0n) < 256)      { aP = xB + (k0n);        aStr = 64 * D_; }         \
        else if ((k0n) < 768) { aP = htB + ((k0n)-256); aStr = 64 * H_; }         \
        else                  { aP = hsB + ((k0n)-768); aStr = 64 * H_; }         \
    } while (0)

#define A_LOAD2(av, aP, aStr, r0_)                                                \
    do {                                                                          \
        av[0][0] = *(const f32x4*)((aP) + (size_t)((r0_)) * (aStr));              \
        av[0][1] = *(const f32x4*)((aP) + (size_t)((r0_)) * (aStr) + 4);          \
        av[1][0] = *(const f32x4*)((aP) + (size_t)((r0_) + 1) * (aStr));          \
        av[1][1] = *(const f32x4*)((aP) + (size_t)((r0_) + 1) * (aStr) + 4);      \
    } while (0)

#define A_CVTWR(dst, av, r0_)                                                     \
    do {                                                                          \
        _Pragma("unroll")                                                         \
        for (int q_ = 0; q_ < 2; ++q_) {                                          \
            union { short8 s; __hip_bfloat16 hh[8]; } o_;                         \
            o_.hh[0] = __float2bfloat16(av[q_][0][0]);                            \
            o_.hh[1] = __float2bfloat16(av[q_][0][1]);                            \
            o_.hh[2] = __float2bfloat16(av[q_][0][2]);                            \
            o_.hh[3] = __float2bfloat16(av[q_][0][3]);                            \
            o_.hh[4] = __float2bfloat16(av[q_][1][0]);                            \
            o_.hh[5] = __float2bfloat16(av[q_][1][1]);                            \
            o_.hh[6] = __float2bfloat16(av[q_][1][2]);                            \
            o_.hh[7] = __float2bfloat16(av[q_][1][3]);                            \
            *(short8*)((dst) + ((r0_) + q_) * 4096 + aWr) = o_.s;                 \
        }                                                                         \
    } while (0)

    // ---- fragment read offsets: addr(shorts) = row*64 + (g ^ xr)*8.
    int arow64[2], brow64[5];
#pragma unroll
    for (int i = 0; i < 2; ++i) arow64[i] = (wm * 64 + i * 32 + l31) * 64;
#pragma unroll
    for (int j = 0; j < 5; ++j) brow64[j] = (wn * 160 + j * 32 + l31) * 64;

#define KSTEP(ks_)                                                                     \
    do {                                                                               \
        int po_ = (((ks_) * 2 + half) ^ xr) * 8;                                       \
        short8 a0 = *(const short8*)(sAc + arow64[0] + po_);                           \
        short8 a1 = *(const short8*)(sAc + arow64[1] + po_);                           \
        short8 b0 = *(const short8*)(sBc + brow64[0] + po_);                           \
        short8 b1 = *(const short8*)(sBc + brow64[1] + po_);                           \
        short8 b2 = *(const short8*)(sBc + brow64[2] + po_);                           \
        short8 b3 = *(const short8*)(sBc + brow64[3] + po_);                           \
        short8 b4 = *(const short8*)(sBc + brow64[4] + po_);                           \
        __builtin_amdgcn_s_setprio(1);                                                 \
        acc[0][0] = __builtin_amdgcn_mfma_f32_32x32x16_bf16(a0, b0, acc[0][0], 0, 0, 0); \
        acc[1][0] = __builtin_amdgcn_mfma_f32_32x32x16_bf16(a1, b0, acc[1][0], 0, 0, 0); \
        acc[0][1] = __builtin_amdgcn_mfma_f32_32x32x16_bf16(a0, b1, acc[0][1], 0, 0, 0); \
        acc[1][1] = __builtin_amdgcn_mfma_f32_32x32x16_bf16(a1, b1, acc[1][1], 0, 0, 0); \
        acc[0][2] = __builtin_amdgcn_mfma_f32_32x32x16_bf16(a0, b2, acc[0][2], 0, 0, 0); \
        acc[1][2] = __builtin_amdgcn_mfma_f32_32x32x16_bf16(a1, b2, acc[1][2], 0, 0, 0); \
        acc[0][3] = __builtin_amdgcn_mfma_f32_32x32x16_bf16(a0, b3, acc[0][3], 0, 0, 0); \
        acc[1][3] = __builtin_amdgcn_mfma_f32_32x32x16_bf16(a1, b3, acc[1][3], 0, 0, 0); \
        acc[0][4] = __builtin_amdgcn_mfma_f32_32x32x16_bf16(a0, b4, acc[0][4], 0, 0, 0); \
        acc[1][4] = __builtin_amdgcn_mfma_f32_32x32x16_bf16(a1, b4, acc[1][4], 0, 0, 0); \
        __builtin_amdgcn_s_setprio(0);                                                 \
    } while (0)

    // ---- prologue: stage K-tile 0 (k0=0 -> x source) ----
    {
        STG_B(sB[0], 0);
        const float* aP; int aStr;
        A_SRC(0, aP, aStr);
        f32x4 av[2][2];
        A_LOAD2(av, aP, aStr, 0); A_CVTWR(sA[0], av, 0);
        A_LOAD2(av, aP, aStr, 2); A_CVTWR(sA[0], av, 2);
    }
    __syncthreads();

    const int nt = K_ / BK_;   // 20
    for (int t = 0; t < nt; ++t) {
        const int cur = t & 1;
        const unsigned short* sAc = sA[cur];
        const unsigned short* sBc = sB[cur];
        unsigned short* sAn = sA[cur ^ 1];
        unsigned short* sBn = sB[cur ^ 1];
        const bool pf = (t + 1 < nt);
        const int kon = (t + 1) * BK_;

        const float* aP = nullptr; int aStr = 0;
        f32x4 av[2][2];
        if (pf) {
            A_SRC(kon, aP, aStr);
            STG_B(sBn, kon);            // fire-and-forget, lands by barrier
            A_LOAD2(av, aP, aStr, 0);   // batch 1 in flight over ks0/ks1
        }
        KSTEP(0);
        KSTEP(1);
        if (pf) {
            A_CVTWR(sAn, av, 0);        // batch 1 done (had ~2 ks of latency)
            A_LOAD2(av, aP, aStr, 2);   // batch 2 in flight over ks2/ks3
        }
        KSTEP(2);
        KSTEP(3);
        if (pf) A_CVTWR(sAn, av, 2);
        __syncthreads();                // drains GLD16s + ds_writes (one/step)
    }
#undef KSTEP
#undef STG_B
#undef A_SRC
#undef A_LOAD2
#undef A_CVTWR

    // ---- lane-local LSTM epilogue ----
    // 32x32 C/D layout: col = lane&31 (h), row = (r&3) + 8*(r>>2) + 4*half.
#pragma unroll
    for (int i = 0; i < 2; ++i) {
        int rbase = m0 + wm * 64 + i * 32 + 4 * half;
#pragma unroll
        for (int r = 0; r < 16; ++r) {
            int row = rbase + (r & 3) + 8 * (r >> 2);
            size_t idx = (size_t)row * H_ + h;
            float i_n  = sigf(acc[i][0][r] + Bi);
            float fs_n = sigf(acc[i][1][r] + Bfs);
            float ft_n = sigf(acc[i][2][r] + Bft);
            float o_n  = sigf(acc[i][3][r] + Bo);
            float c_n  = tanhfast(acc[i][4][r] + Bc);
            float ch   = i_n * c_n + ft_n * ct[idx] + fs_n * cs[idx];
            out[idx] = o_n * tanhfast(ch);
            out[(size_t)B_ * H_ + idx] = ch;
        }
    }
}

// ---------------------------------------------------------------------------
// Fallback (ws too small): one block per row, fp32 direct. Slow but correct.
// ---------------------------------------------------------------------------
struct AllW {
    const float* U[5];
    const float* Wt[5];
    const float* Ws[5];
    const float* bias[5];
};

__global__ __launch_bounds__(512) void fallback_kernel(const float* __restrict__ x,
                                                       const float* __restrict__ ht,
                                                       const float* __restrict__ hs,
                                                       const float* __restrict__ ct,
                                                       const float* __restrict__ cs,
                                                       AllW w, float* __restrict__ out) {
    __shared__ float arow[K_];
    int b = blockIdx.x;
    int h = threadIdx.x;
    for (int k = h; k < K_; k += 512) {
        float v;
        if (k < D_)           v = x[b * D_ + k];
        else if (k < D_ + H_) v = ht[b * H_ + k - D_];
        else                  v = hs[b * H_ + k - D_ - H_];
        arow[k] = v;
    }
    __syncthreads();
    float g[5];
    for (int gi = 0; gi < 5; ++gi) {
        float s = w.bias[gi][h];
        const float* U = w.U[gi];
        for (int k = 0; k < D_; ++k) s += arow[k] * U[(size_t)k * H_ + h];
        const float* Wt = w.Wt[gi];
        for (int k = 0; k < H_; ++k) s += arow[D_ + k] * Wt[(size_t)k * H_ + h];
        const float* Ws = w.Ws[gi];
        for (int k = 0; k < H_; ++k) s += arow[D_ + H_ + k] * Ws[(size_t)k * H_ + h];
        g[gi] = s;
    }
    int idx = b * H_ + h;
    float i_n = sigf(g[0]), fs_n = sigf(g[1]), ft_n = sigf(g[2]), o_n = sigf(g[3]);
    float c_n = tanhfast(g[4]);
    float ch  = i_n * c_n + ft_n * ct[idx] + fs_n * cs[idx];
    out[idx] = o_n * tanhfast(ch);
    out[(size_t)B_ * H_ + idx] = ch;
}

// ---------------------------------------------------------------------------
extern "C" void kernel_launch(void* const* d_in, const int* in_sizes, int n_in,
                              void* d_out, int out_size, void* d_ws, size_t ws_size,
                              hipStream_t stream) {
    const float* x  = (const float*)d_in[0];
    const float* ht = (const float*)d_in[1];
    const float* hs = (const float*)d_in[2];
    const float* ct = (const float*)d_in[3];
    const float* cs = (const float*)d_in[4];

    WPtrs wp;
    AllW  aw;
    const float* bias[5];
    for (int g = 0; g < 5; ++g) {
        wp.U[g]  = (const float*)d_in[5 + g * 4 + 0];
        wp.Wt[g] = (const float*)d_in[5 + g * 4 + 1];
        wp.Ws[g] = (const float*)d_in[5 + g * 4 + 2];
        bias[g]  = (const float*)d_in[5 + g * 4 + 3];
        aw.U[g] = wp.U[g]; aw.Wt[g] = wp.Wt[g]; aw.Ws[g] = wp.Ws[g]; aw.bias[g] = bias[g];
    }
    float* out = (float*)d_out;

    size_t szW    = (size_t)N_ * K_ * 2;               // 6.25 MB (WT)
    size_t cntOff = (szW + 127) & ~(size_t)127;        // barrier counter slot

    if (ws_size >= cntOff + 128) {
        __hip_bfloat16* WT  = (__hip_bfloat16*)d_ws;
        unsigned int*   cnt = (unsigned int*)((char*)d_ws + cntOff);
        hipMemsetAsync(cnt, 0, 128, stream);           // re-zeroed every replay
        fused_kernel<<<256, 512, 0, stream>>>(
            x, ht, hs, wp, WT, cnt, ct, cs,
            bias[0], bias[1], bias[2], bias[3], bias[4], out);
    } else {
        fallback_kernel<<<B_, 512, 0, stream>>>(x, ht, hs, ct, cs, aw, out);
    }
}